// Round 3
// baseline (411.505 us; speedup 1.0000x reference)
//
#include <hip/hip_runtime.h>
#include <cstdint>
#include <cstddef>

#define S_LEN 4096
#define B_SZ 16
#define H2D 1024
#define P_PER_B 64      // one partial per BLOCK per batch (64 s-rows each, LDS-merged)

__device__ __forceinline__ float dot4(float4 a, float4 b) {
    return a.x * b.x + a.y * b.y + a.z * b.z + a.w * b.w;
}
__device__ __forceinline__ void axpy4(float4& acc, float w, float4 v) {
    acc.x += w * v.x; acc.y += w * v.y; acc.z += w * v.z; acc.w += w * v.w;
}

// altered[b][i] = attn_b[i] + sum_j state[b][j]*attn_w[i][j]; one wave per row i.
__global__ __launch_bounds__(256) void k_altered(const float* __restrict__ state,
                                                 const float* __restrict__ attn_w,
                                                 const float* __restrict__ attn_b,
                                                 float* __restrict__ altered) {
    const int i = (blockIdx.x * 256 + threadIdx.x) >> 6;  // 0..1023
    const int lane = threadIdx.x & 63;
    const float4* w4 = (const float4*)(attn_w + (size_t)i * H2D);
    float4 r[4];
#pragma unroll
    for (int j = 0; j < 4; ++j) r[j] = w4[lane + 64 * j];
    const float bias = attn_b[i];
    for (int b = 0; b < B_SZ; ++b) {
        const float4* s4 = (const float4*)(state + b * H2D);
        float p = 0.f;
#pragma unroll
        for (int j = 0; j < 4; ++j) p += dot4(r[j], s4[lane + 64 * j]);
#pragma unroll
        for (int off = 32; off; off >>= 1) p += __shfl_xor(p, off, 64);
        if (lane == 0) altered[b * H2D + i] = p + bias;
    }
}

// Single pass over enc (256 MB read ONCE): per-wave online softmax over 16 rows
// in groups of 2 (live e-state 32 VGPRs, no spill pressure, no forced bounds),
// then LDS merge of the 4 wave-partials -> ONE partial per block.
// grid (64, B_SZ) = 1024 blocks -> 4 blocks/CU, 16 waves/CU.
__global__ __launch_bounds__(256) void k_flash(const float* __restrict__ enc,
                                               const float* __restrict__ altered,
                                               float* __restrict__ w_raw,
                                               float* __restrict__ pm,
                                               float* __restrict__ pl,
                                               float* __restrict__ pacc) {
    const int b = blockIdx.y;
    const int wave = threadIdx.x >> 6, lane = threadIdx.x & 63;
    const int blk = blockIdx.x;            // 0..63
    const int s0 = blk * 64 + wave * 16;   // 16 rows per wave

    const float4* a4 = (const float4*)(altered + b * H2D);
    float4 af[4];
#pragma unroll
    for (int j = 0; j < 4; ++j) af[j] = a4[lane + 64 * j];

    float m = -1e30f, l = 0.f;
    float4 acc[4];
#pragma unroll
    for (int j = 0; j < 4; ++j) acc[j] = make_float4(0.f, 0.f, 0.f, 0.f);

    for (int k = 0; k < 16; k += 2) {
        float4 e[2][4];
        float p[2];
#pragma unroll
        for (int r = 0; r < 2; ++r) {
            const float4* e4 = (const float4*)(enc + ((size_t)(s0 + k + r) * B_SZ + b) * H2D);
#pragma unroll
            for (int j = 0; j < 4; ++j) e[r][j] = e4[lane + 64 * j];
        }
#pragma unroll
        for (int r = 0; r < 2; ++r) {
            p[r] = 0.f;
#pragma unroll
            for (int j = 0; j < 4; ++j) p[r] += dot4(af[j], e[r][j]);
        }
#pragma unroll
        for (int off = 32; off; off >>= 1)
#pragma unroll
            for (int r = 0; r < 2; ++r) p[r] += __shfl_xor(p[r], off, 64);
        if (lane == 0) {
            w_raw[b * S_LEN + s0 + k]     = p[0];
            w_raw[b * S_LEN + s0 + k + 1] = p[1];
        }
        // one online-softmax merge for the 2 rows
        const float mn = fmaxf(m, fmaxf(p[0], p[1]));
        const float sc = __expf(m - mn);
        const float ex0 = __expf(p[0] - mn);
        const float ex1 = __expf(p[1] - mn);
        l = l * sc + ex0 + ex1;
#pragma unroll
        for (int j = 0; j < 4; ++j) {
            acc[j].x *= sc; acc[j].y *= sc; acc[j].z *= sc; acc[j].w *= sc;
            axpy4(acc[j], ex0, e[0][j]);
            axpy4(acc[j], ex1, e[1][j]);
        }
        m = mn;
    }

    // ---- block-level merge of the 4 wave partials (pacc stays at 4 MB)
    __shared__ float4 lacc[4][256];
    __shared__ float lm[4], ll[4];
#pragma unroll
    for (int j = 0; j < 4; ++j) lacc[wave][lane + 64 * j] = acc[j];
    if (lane == 0) { lm[wave] = m; ll[wave] = l; }
    __syncthreads();
    const int t = threadIdx.x;
    const float M = fmaxf(fmaxf(lm[0], lm[1]), fmaxf(lm[2], lm[3]));
    const float e0 = __expf(lm[0] - M), e1 = __expf(lm[1] - M);
    const float e2 = __expf(lm[2] - M), e3 = __expf(lm[3] - M);
    float4 s = make_float4(0.f, 0.f, 0.f, 0.f);
    axpy4(s, e0, lacc[0][t]); axpy4(s, e1, lacc[1][t]);
    axpy4(s, e2, lacc[2][t]); axpy4(s, e3, lacc[3][t]);
    const size_t pi = (size_t)(b * P_PER_B + blk);
    if (t == 0) {
        pm[pi] = M;
        pl[pi] = e0 * ll[0] + e1 * ll[1] + e2 * ll[2] + e3 * ll[3];
    }
    ((float4*)(pacc + pi * H2D))[t] = s;
}

// Per batch: reduce 64 (m,l) partials -> M, 1/Z; write cexp; normalized
// weights; zero out_attn for the atomic combine. grid B_SZ x 256 thr.
__global__ __launch_bounds__(256) void k_fin1(const float* __restrict__ pm,
                                              const float* __restrict__ pl,
                                              const float* __restrict__ w_raw,
                                              float* __restrict__ cexp,
                                              float* __restrict__ MZ,
                                              float* __restrict__ out_attn,
                                              float* __restrict__ out_nw) {
    const int b = blockIdx.x, t = threadIdx.x;
    const int wave = t >> 6, lane = t & 63;
    __shared__ float sw[4];
    const float mv = (t < P_PER_B) ? pm[b * P_PER_B + t] : -1e30f;
    float mm = mv;
#pragma unroll
    for (int off = 32; off; off >>= 1) mm = fmaxf(mm, __shfl_xor(mm, off, 64));
    if (lane == 0) sw[wave] = mm;
    __syncthreads();
    const float M = fmaxf(fmaxf(sw[0], sw[1]), fmaxf(sw[2], sw[3]));
    const float e = (t < P_PER_B) ? __expf(mv - M) : 0.f;
    float zl = (t < P_PER_B) ? e * pl[b * P_PER_B + t] : 0.f;
#pragma unroll
    for (int off = 32; off; off >>= 1) zl += __shfl_xor(zl, off, 64);
    __syncthreads();
    if (lane == 0) sw[wave] = zl;
    __syncthreads();
    const float invZ = 1.f / (sw[0] + sw[1] + sw[2] + sw[3]);
    if (t < P_PER_B) cexp[b * P_PER_B + t] = e;
    if (t == 0) { MZ[2 * b] = M; MZ[2 * b + 1] = invZ; }
    // zero out_attn row (poisoned 0xAA by harness; k_fin2 atomically accumulates)
    ((float4*)(out_attn + b * H2D))[t] = make_float4(0.f, 0.f, 0.f, 0.f);
    // normalized weights
    const float4* wr = (const float4*)(w_raw + b * S_LEN);
    float4* on = (float4*)(out_nw + b * S_LEN);
#pragma unroll
    for (int i = 0; i < 4; ++i) {
        const int idx = t + 256 * i;
        const float4 v = wr[idx];
        on[idx] = make_float4(__expf(v.x - M) * invZ, __expf(v.y - M) * invZ,
                              __expf(v.z - M) * invZ, __expf(v.w - M) * invZ);
    }
}

// Combine: out_attn[b][d] += invZ * sum_{p in group} cexp[p]*pacc[b][p][d].
// grid (B_SZ, 4); each block handles 16 partials; thread t = float4 col.
__global__ __launch_bounds__(256) void k_fin2(const float* __restrict__ pacc,
                                              const float* __restrict__ cexp,
                                              const float* __restrict__ MZ,
                                              float* __restrict__ out_attn) {
    const int b = blockIdx.x, pg = blockIdx.y, t = threadIdx.x;
    const float invZ = MZ[2 * b + 1];
    const float* cb = cexp + b * P_PER_B + pg * 16;
    const float4* base = (const float4*)(pacc + (size_t)(b * P_PER_B + pg * 16) * H2D);
    float4 s = make_float4(0.f, 0.f, 0.f, 0.f);
#pragma unroll
    for (int p = 0; p < 16; ++p) {
        const float c = cb[p];
        axpy4(s, c, base[(size_t)p * 256 + t]);
    }
    float* o = out_attn + b * H2D + 4 * t;
    atomicAdd(o + 0, s.x * invZ);
    atomicAdd(o + 1, s.y * invZ);
    atomicAdd(o + 2, s.z * invZ);
    atomicAdd(o + 3, s.w * invZ);
}

extern "C" void kernel_launch(void* const* d_in, const int* in_sizes, int n_in,
                              void* d_out, int out_size, void* d_ws, size_t ws_size,
                              hipStream_t stream) {
    const float* enc    = (const float*)d_in[0];  // [S, B, 2H]
    const float* state  = (const float*)d_in[1];  // [B, 2H]
    // d_in[2] previous_attention, d_in[5] time_w, d_in[6] time_b: dead branch, unused
    const float* attn_w = (const float*)d_in[3];  // [2H, 2H]
    const float* attn_b = (const float*)d_in[4];  // [2H]

    float* ws = (float*)d_ws;
    float* altered = ws;                   // 16384 floats
    float* w_raw   = altered + 16384;      // 65536
    float* pm      = w_raw + 65536;        // 1024 (B*64)
    float* pl      = pm + 1024;            // 1024
    float* cexp    = pl + 1024;            // 1024
    float* MZ      = cexp + 1024;          // 32 (padded 1024)
    float* pacc    = MZ + 1024;            // 16*64*1024 floats (4 MB)

    float* out_attn = (float*)d_out;               // [B, 2H]
    float* out_nw   = (float*)d_out + B_SZ * H2D;  // [B, S]

    hipLaunchKernelGGL(k_altered, dim3(256), dim3(256), 0, stream,
                       state, attn_w, attn_b, altered);
    hipLaunchKernelGGL(k_flash, dim3(64, B_SZ), dim3(256), 0, stream,
                       enc, altered, w_raw, pm, pl, pacc);
    hipLaunchKernelGGL(k_fin1, dim3(B_SZ), dim3(256), 0, stream,
                       pm, pl, w_raw, cexp, MZ, out_attn, out_nw);
    hipLaunchKernelGGL(k_fin2, dim3(B_SZ, 4), dim3(256), 0, stream,
                       pacc, cexp, MZ, out_attn);
}

// Round 4
// 408.846 us; speedup vs baseline: 1.0065x; 1.0065x over previous
//
#include <hip/hip_runtime.h>
#include <cstdint>
#include <cstddef>

#define S_LEN 4096
#define B_SZ 16
#define H2D 1024
#define P_PER_B 64      // one partial per BLOCK per batch (64 s-rows each, LDS-merged)

__device__ __forceinline__ float dot4(float4 a, float4 b) {
    return a.x * b.x + a.y * b.y + a.z * b.z + a.w * b.w;
}
__device__ __forceinline__ void axpy4(float4& acc, float w, float4 v) {
    acc.x += w * v.x; acc.y += w * v.y; acc.z += w * v.z; acc.w += w * v.w;
}

// altered[b][i] = attn_b[i] + sum_j state[b][j]*attn_w[i][j]; one wave per row i.
__global__ __launch_bounds__(256) void k_altered(const float* __restrict__ state,
                                                 const float* __restrict__ attn_w,
                                                 const float* __restrict__ attn_b,
                                                 float* __restrict__ altered) {
    const int i = (blockIdx.x * 256 + threadIdx.x) >> 6;  // 0..1023
    const int lane = threadIdx.x & 63;
    const float4* w4 = (const float4*)(attn_w + (size_t)i * H2D);
    float4 r[4];
#pragma unroll
    for (int j = 0; j < 4; ++j) r[j] = w4[lane + 64 * j];
    const float bias = attn_b[i];
    for (int b = 0; b < B_SZ; ++b) {
        const float4* s4 = (const float4*)(state + b * H2D);
        float p = 0.f;
#pragma unroll
        for (int j = 0; j < 4; ++j) p += dot4(r[j], s4[lane + 64 * j]);
#pragma unroll
        for (int off = 32; off; off >>= 1) p += __shfl_xor(p, off, 64);
        if (lane == 0) altered[b * H2D + i] = p + bias;
    }
}

// Single pass over enc (256 MB read ONCE): per-wave online softmax over 16 rows,
// 4-row groups (one rescale per 4 rows; half the shuffle stages of 2-row),
// then LDS merge of the 4 wave-partials -> ONE partial per block (pacc 4 MB).
// grid (64, B_SZ) = 1024 blocks -> 4 blocks/CU, 16 waves/CU.
__global__ __launch_bounds__(256, 4) void k_flash(const float* __restrict__ enc,
                                                  const float* __restrict__ altered,
                                                  float* __restrict__ w_raw,
                                                  float* __restrict__ pm,
                                                  float* __restrict__ pl,
                                                  float* __restrict__ pacc) {
    const int b = blockIdx.y;
    const int wave = threadIdx.x >> 6, lane = threadIdx.x & 63;
    const int blk = blockIdx.x;            // 0..63
    const int s0 = blk * 64 + wave * 16;   // 16 rows per wave

    const float4* a4 = (const float4*)(altered + b * H2D);
    float4 af[4];
#pragma unroll
    for (int j = 0; j < 4; ++j) af[j] = a4[lane + 64 * j];

    float m = -1e30f, l = 0.f;
    float4 acc[4];
#pragma unroll
    for (int j = 0; j < 4; ++j) acc[j] = make_float4(0.f, 0.f, 0.f, 0.f);

    for (int k = 0; k < 16; k += 4) {
        float4 e[4][4];
        float p[4];
#pragma unroll
        for (int r = 0; r < 4; ++r) {
            const float4* e4 = (const float4*)(enc + ((size_t)(s0 + k + r) * B_SZ + b) * H2D);
#pragma unroll
            for (int j = 0; j < 4; ++j) e[r][j] = e4[lane + 64 * j];
        }
#pragma unroll
        for (int r = 0; r < 4; ++r) {
            p[r] = 0.f;
#pragma unroll
            for (int j = 0; j < 4; ++j) p[r] += dot4(af[j], e[r][j]);
        }
#pragma unroll
        for (int off = 32; off; off >>= 1)
#pragma unroll
            for (int r = 0; r < 4; ++r) p[r] += __shfl_xor(p[r], off, 64);
        if (lane == 0) {
#pragma unroll
            for (int r = 0; r < 4; ++r) w_raw[b * S_LEN + s0 + k + r] = p[r];
        }
        // one online-softmax merge for all 4 rows
        float mn = m;
#pragma unroll
        for (int r = 0; r < 4; ++r) mn = fmaxf(mn, p[r]);
        const float sc = __expf(m - mn);
        float ex[4];
#pragma unroll
        for (int r = 0; r < 4; ++r) ex[r] = __expf(p[r] - mn);
        l = l * sc + ex[0] + ex[1] + ex[2] + ex[3];
#pragma unroll
        for (int j = 0; j < 4; ++j) {
            acc[j].x *= sc; acc[j].y *= sc; acc[j].z *= sc; acc[j].w *= sc;
#pragma unroll
            for (int r = 0; r < 4; ++r) axpy4(acc[j], ex[r], e[r][j]);
        }
        m = mn;
    }

    // ---- block-level merge of the 4 wave partials (saves 24 MB of pacc traffic)
    __shared__ float4 lacc[4][256];
    __shared__ float lm[4], ll[4];
#pragma unroll
    for (int j = 0; j < 4; ++j) lacc[wave][lane + 64 * j] = acc[j];
    if (lane == 0) { lm[wave] = m; ll[wave] = l; }
    __syncthreads();
    const int t = threadIdx.x;
    const float M = fmaxf(fmaxf(lm[0], lm[1]), fmaxf(lm[2], lm[3]));
    const float e0 = __expf(lm[0] - M), e1 = __expf(lm[1] - M);
    const float e2 = __expf(lm[2] - M), e3 = __expf(lm[3] - M);
    float4 s = make_float4(0.f, 0.f, 0.f, 0.f);
    axpy4(s, e0, lacc[0][t]); axpy4(s, e1, lacc[1][t]);
    axpy4(s, e2, lacc[2][t]); axpy4(s, e3, lacc[3][t]);
    const size_t pi = (size_t)(b * P_PER_B + blk);
    if (t == 0) {
        pm[pi] = M;
        pl[pi] = e0 * ll[0] + e1 * ll[1] + e2 * ll[2] + e3 * ll[3];
    }
    ((float4*)(pacc + pi * H2D))[t] = s;
}

// Per batch: reduce 64 (m,l) partials -> M, 1/Z; write cexp; normalized
// weights; zero out_attn for the atomic combine. grid B_SZ x 256 thr.
__global__ __launch_bounds__(256) void k_fin1(const float* __restrict__ pm,
                                              const float* __restrict__ pl,
                                              const float* __restrict__ w_raw,
                                              float* __restrict__ cexp,
                                              float* __restrict__ MZ,
                                              float* __restrict__ out_attn,
                                              float* __restrict__ out_nw) {
    const int b = blockIdx.x, t = threadIdx.x;
    const int wave = t >> 6, lane = t & 63;
    __shared__ float sw[4];
    const float mv = (t < P_PER_B) ? pm[b * P_PER_B + t] : -1e30f;
    float mm = mv;
#pragma unroll
    for (int off = 32; off; off >>= 1) mm = fmaxf(mm, __shfl_xor(mm, off, 64));
    if (lane == 0) sw[wave] = mm;
    __syncthreads();
    const float M = fmaxf(fmaxf(sw[0], sw[1]), fmaxf(sw[2], sw[3]));
    const float e = (t < P_PER_B) ? __expf(mv - M) : 0.f;
    float zl = (t < P_PER_B) ? e * pl[b * P_PER_B + t] : 0.f;
#pragma unroll
    for (int off = 32; off; off >>= 1) zl += __shfl_xor(zl, off, 64);
    __syncthreads();
    if (lane == 0) sw[wave] = zl;
    __syncthreads();
    const float invZ = 1.f / (sw[0] + sw[1] + sw[2] + sw[3]);
    if (t < P_PER_B) cexp[b * P_PER_B + t] = e;
    if (t == 0) { MZ[2 * b] = M; MZ[2 * b + 1] = invZ; }
    // zero out_attn row (poisoned 0xAA by harness; k_fin2 atomically accumulates)
    ((float4*)(out_attn + b * H2D))[t] = make_float4(0.f, 0.f, 0.f, 0.f);
    // normalized weights
    const float4* wr = (const float4*)(w_raw + b * S_LEN);
    float4* on = (float4*)(out_nw + b * S_LEN);
#pragma unroll
    for (int i = 0; i < 4; ++i) {
        const int idx = t + 256 * i;
        const float4 v = wr[idx];
        on[idx] = make_float4(__expf(v.x - M) * invZ, __expf(v.y - M) * invZ,
                              __expf(v.z - M) * invZ, __expf(v.w - M) * invZ);
    }
}

// Combine: out_attn[b][d] += invZ * sum_{p in group} cexp[p]*pacc[b][p][d].
// grid (B_SZ, 4); each block handles 16 partials; thread t = float4 col.
__global__ __launch_bounds__(256) void k_fin2(const float* __restrict__ pacc,
                                              const float* __restrict__ cexp,
                                              const float* __restrict__ MZ,
                                              float* __restrict__ out_attn) {
    const int b = blockIdx.x, pg = blockIdx.y, t = threadIdx.x;
    const float invZ = MZ[2 * b + 1];
    const float* cb = cexp + b * P_PER_B + pg * 16;
    const float4* base = (const float4*)(pacc + (size_t)(b * P_PER_B + pg * 16) * H2D);
    float4 s = make_float4(0.f, 0.f, 0.f, 0.f);
#pragma unroll
    for (int p = 0; p < 16; ++p) {
        const float c = cb[p];
        axpy4(s, c, base[(size_t)p * 256 + t]);
    }
    float* o = out_attn + b * H2D + 4 * t;
    atomicAdd(o + 0, s.x * invZ);
    atomicAdd(o + 1, s.y * invZ);
    atomicAdd(o + 2, s.z * invZ);
    atomicAdd(o + 3, s.w * invZ);
}

extern "C" void kernel_launch(void* const* d_in, const int* in_sizes, int n_in,
                              void* d_out, int out_size, void* d_ws, size_t ws_size,
                              hipStream_t stream) {
    const float* enc    = (const float*)d_in[0];  // [S, B, 2H]
    const float* state  = (const float*)d_in[1];  // [B, 2H]
    // d_in[2] previous_attention, d_in[5] time_w, d_in[6] time_b: dead branch, unused
    const float* attn_w = (const float*)d_in[3];  // [2H, 2H]
    const float* attn_b = (const float*)d_in[4];  // [2H]

    float* ws = (float*)d_ws;
    float* altered = ws;                   // 16384 floats
    float* w_raw   = altered + 16384;      // 65536
    float* pm      = w_raw + 65536;        // 1024 (B*64)
    float* pl      = pm + 1024;            // 1024
    float* cexp    = pl + 1024;            // 1024
    float* MZ      = cexp + 1024;          // 32 (padded 1024)
    float* pacc    = MZ + 1024;            // 16*64*1024 floats (4 MB)

    float* out_attn = (float*)d_out;               // [B, 2H]
    float* out_nw   = (float*)d_out + B_SZ * H2D;  // [B, S]

    hipLaunchKernelGGL(k_altered, dim3(256), dim3(256), 0, stream,
                       state, attn_w, attn_b, altered);
    hipLaunchKernelGGL(k_flash, dim3(64, B_SZ), dim3(256), 0, stream,
                       enc, altered, w_raw, pm, pl, pacc);
    hipLaunchKernelGGL(k_fin1, dim3(B_SZ), dim3(256), 0, stream,
                       pm, pl, w_raw, cexp, MZ, out_attn, out_nw);
    hipLaunchKernelGGL(k_fin2, dim3(B_SZ, 4), dim3(256), 0, stream,
                       pacc, cexp, MZ, out_attn);
}